// Round 4
// baseline (258.267 us; speedup 1.0000x reference)
//
#include <hip/hip_runtime.h>
#include <math.h>

// OfflinePrepareLayer: N=200000 nodes, E=6400000 edges, ENV=3, HIST=15, R=0.05
// Outputs concatenated in d_out (all f32):
//   [0)              node_feature  (N,21)
//   [N*21)           edge_feature  (E,4)
//   [N*21+E*4)       current_v     (N,3)

static constexpr float INV_R = 20.0f;   // 1/0.05

// clang native vector type — required by __builtin_nontemporal_store
// (HIP's float4 is a class and is rejected by the builtin).
typedef float f32x4 __attribute__((ext_vector_type(4)));

// node_feature[n, c]:
//   c in [0,15): hist_v[n, c]                  (VEL_MEAN=0, VEL_STD=1)
//   c in [15,21): j=c-15; clamp((pos[n, j/2] - bnd[j]) * 20, -1, 1)
// current_v[n, c] = hist_v[n, c], c in [0,3)
__global__ void node_kernel(const float* __restrict__ pos,
                            const float* __restrict__ hist_v,
                            const float* __restrict__ bnd,
                            float* __restrict__ node_feat,
                            float* __restrict__ cur_v,
                            int n) {
    const int stride = gridDim.x * blockDim.x;
    const int tid = blockIdx.x * blockDim.x + threadIdx.x;

    const int total_nf = n * 21;
    for (int idx = tid; idx < total_nf; idx += stride) {
        const int node = idx / 21;
        const int c = idx - node * 21;
        float v;
        if (c < 15) {
            v = hist_v[node * 15 + c];
        } else {
            const int j = c - 15;
            const float p = pos[node * 3 + (j >> 1)];
            v = (p - bnd[j]) * INV_R;
            v = fminf(1.0f, fmaxf(-1.0f, v));
        }
        node_feat[idx] = v;
    }

    const int total_cv = n * 3;
    for (int idx = tid; idx < total_cv; idx += stride) {
        const int node = idx / 3;
        const int c = idx - node * 3;
        cur_v[idx] = hist_v[node * 15 + c];
    }
}

// edge_feature[e] = ((pos[src]-pos[dst])*20, ||.||)  -> 16B nontemporal store
__global__ void edge_kernel(const float* __restrict__ pos,
                            const int* __restrict__ src,
                            const int* __restrict__ dst,
                            f32x4* __restrict__ edge_feat,
                            int e) {
    const int stride = gridDim.x * blockDim.x;
    for (int i = blockIdx.x * blockDim.x + threadIdx.x; i < e; i += stride) {
        const int s = src[i] * 3;
        const int d = dst[i] * 3;
        const float rx = (pos[s + 0] - pos[d + 0]) * INV_R;
        const float ry = (pos[s + 1] - pos[d + 1]) * INV_R;
        const float rz = (pos[s + 2] - pos[d + 2]) * INV_R;
        const float dis = sqrtf(rx * rx + ry * ry + rz * rz);
        // Streaming write-only output: keep it out of L2 so pos stays cached.
        f32x4 out = {rx, ry, rz, dis};
        __builtin_nontemporal_store(out, &edge_feat[i]);
    }
}

extern "C" void kernel_launch(void* const* d_in, const int* in_sizes, int n_in,
                              void* d_out, int out_size, void* d_ws, size_t ws_size,
                              hipStream_t stream) {
    const float* pos    = (const float*)d_in[0];   // (N,3)
    const float* hist_v = (const float*)d_in[1];   // (N,15)
    const float* bnd    = (const float*)d_in[2];   // (6,)
    const int*   src    = (const int*)d_in[3];     // (E,)
    const int*   dst    = (const int*)d_in[4];     // (E,)

    const int N = in_sizes[0] / 3;
    const int E = in_sizes[3];

    float* out       = (float*)d_out;
    float* node_feat = out;                                   // N*21
    float* edge_feat = out + (size_t)N * 21;                  // E*4 (16B-aligned: N*21*4 % 16 == 0)
    float* cur_v     = out + (size_t)N * 21 + (size_t)E * 4;  // N*3

    const int block = 256;

    // Node work: N*21 ~ 4.2M elements. 1024 blocks, grid-stride.
    node_kernel<<<1024, block, 0, stream>>>(pos, hist_v, bnd, node_feat, cur_v, N);

    // Edge work: E = 6.4M threads-worth. 2048 blocks, grid-stride.
    edge_kernel<<<2048, block, 0, stream>>>(pos, src, dst, (f32x4*)edge_feat, E);
}

// Round 7
// 243.915 us; speedup vs baseline: 1.0588x; 1.0588x over previous
//
#include <hip/hip_runtime.h>
#include <math.h>

// OfflinePrepareLayer: N=200000 nodes, E=6400000 edges, ENV=3, HIST=15, R=0.05
// d_out (f32, concat): node_feature (N,21) | edge_feature (E,4) | current_v (N,3)
//
// Round-4 evidence: edge gathers are request-throughput bound (8.7 cyc/edge,
// 1.33 TB/s, VALUBusy 5%). Fixes: vectorized 12B pos gathers, 4 edges/thread
// for MLP, node work fused in (first blocks) to overlap with gather latency.

static constexpr float INV_R = 20.0f;   // 1/0.05

typedef float f32x4 __attribute__((ext_vector_type(4)));
typedef int   i32x4 __attribute__((ext_vector_type(4)));
// 8B vector load with 4B alignment promise (pos rows are 12B-aligned -> 4B only)
typedef float f32x2 __attribute__((ext_vector_type(2), aligned(4)));

__global__ __launch_bounds__(256) void fused_kernel(
    const float* __restrict__ pos,      // (N,3)
    const float* __restrict__ hist_v,   // (N,15)
    const float* __restrict__ bnd,      // (6,)
    const i32x4* __restrict__ src4,     // (E/4,)
    const i32x4* __restrict__ dst4,     // (E/4,)
    float* __restrict__ node_feat,      // (N,21)
    f32x4* __restrict__ edge_feat,      // (E,)  16B-aligned
    float* __restrict__ cur_v,          // (N,3)
    int n, int e4, int node_blocks)
{
    if ((int)blockIdx.x < node_blocks) {
        // ---- node work: grid-stride over N*21 + N*3, coalesced ----
        const int stride = node_blocks * blockDim.x;
        const int tid = blockIdx.x * blockDim.x + threadIdx.x;

        const int total_nf = n * 21;
        for (int idx = tid; idx < total_nf; idx += stride) {
            const int node = idx / 21;
            const int c = idx - node * 21;
            float v;
            if (c < 15) {
                v = hist_v[node * 15 + c];
            } else {
                const int j = c - 15;
                const float p = pos[node * 3 + (j >> 1)];
                v = (p - bnd[j]) * INV_R;
                v = fminf(1.0f, fmaxf(-1.0f, v));
            }
            node_feat[idx] = v;
        }

        const int total_cv = n * 3;
        for (int idx = tid; idx < total_cv; idx += stride) {
            const int node = idx / 3;
            const int c = idx - node * 3;
            cur_v[idx] = hist_v[node * 15 + c];
        }
    } else {
        // ---- edge work: 1 thread per 4 edges ----
        const int t = (blockIdx.x - node_blocks) * blockDim.x + threadIdx.x;
        if (t >= e4) return;

        const i32x4 s4 = src4[t];   // coalesced dwordx4
        const i32x4 d4 = dst4[t];

        // 8 independent 12B gathers; f32x2+scalar adjacent loads -> LSV
        // should merge to global_load_dwordx3 (>=2, <=4 instrs per edge-pair).
        float sx[4], sy[4], sz[4], dx[4], dy[4], dz[4];
#pragma unroll
        for (int k = 0; k < 4; ++k) {
            const float* ps = pos + (size_t)s4[k] * 3;
            const float* pd = pos + (size_t)d4[k] * 3;
            const f32x2 sxy = *(const f32x2*)ps;
            const float szv = ps[2];
            const f32x2 dxy = *(const f32x2*)pd;
            const float dzv = pd[2];
            sx[k] = sxy.x; sy[k] = sxy.y; sz[k] = szv;
            dx[k] = dxy.x; dy[k] = dxy.y; dz[k] = dzv;
        }
#pragma unroll
        for (int k = 0; k < 4; ++k) {
            const float rx = (sx[k] - dx[k]) * INV_R;
            const float ry = (sy[k] - dy[k]) * INV_R;
            const float rz = (sz[k] - dz[k]) * INV_R;
            const float dis = sqrtf(rx * rx + ry * ry + rz * rz);
            f32x4 o = {rx, ry, rz, dis};
            // streaming write-only: bypass L2 so pos stays cached
            __builtin_nontemporal_store(o, &edge_feat[4 * t + k]);
        }
    }
}

extern "C" void kernel_launch(void* const* d_in, const int* in_sizes, int n_in,
                              void* d_out, int out_size, void* d_ws, size_t ws_size,
                              hipStream_t stream) {
    const float* pos    = (const float*)d_in[0];   // (N,3)
    const float* hist_v = (const float*)d_in[1];   // (N,15)
    const float* bnd    = (const float*)d_in[2];   // (6,)
    const int*   src    = (const int*)d_in[3];     // (E,)
    const int*   dst    = (const int*)d_in[4];     // (E,)

    const int N = in_sizes[0] / 3;
    const int E = in_sizes[3];
    const int e4 = E / 4;                          // E = 6.4M, divisible by 4

    float* out       = (float*)d_out;
    float* node_feat = out;                                   // N*21
    float* edge_feat = out + (size_t)N * 21;                  // E*4; byte off N*84 % 16 == 0
    float* cur_v     = out + (size_t)N * 21 + (size_t)E * 4;  // N*3

    const int block = 256;
    const int node_blocks = 1024;                  // ~33 MB coalesced work
    const int edge_blocks = (e4 + block - 1) / block;   // 6250 at E=6.4M

    fused_kernel<<<node_blocks + edge_blocks, block, 0, stream>>>(
        pos, hist_v, bnd, (const i32x4*)src, (const i32x4*)dst,
        node_feat, (f32x4*)edge_feat, cur_v, N, e4, node_blocks);
}